// Round 5
// baseline (136.909 us; speedup 1.0000x reference)
//
#include <hip/hip_runtime.h>
#include <hip/hip_bf16.h>

// Problem constants
#define Wd    96
#define Hd    96
#define HW    9216           // 96*96
#define Bn    4
#define Cn    64             // channels per section
#define C3    192            // 3*Cn
#define On    64             // out channels
#define NPIX  (Bn*HW)        // 36864
#define NFEAT (Bn*Cn*HW)     // 2359296 elements per output tensor
#define NWTB  (9*6*4*512)    // 110592 bf16 frag-linear deform weights
#define NWTB2 (18*2*64*8)    // 18432 bf16 frag-linear offset weights
#define NRB3  (Bn*(HW/32))   // 1152 repack blocks (32-px strips)

// Halo geometry (16-px strip, one image row), staged in TWO channel halves
#define HR    5              // staged rows: yb-2 .. yb+2
#define HC    21             // staged cols: xb-3 .. xb+17
#define HPITCH 208           // bytes per staged pixel per half (192 + 16 pad)
#define NPR   (HR*HC)        // 105 staged pixel rows

typedef __attribute__((ext_vector_type(8))) short s8v;    // 8 bf16
typedef __attribute__((ext_vector_type(4))) unsigned int u4v;
typedef __attribute__((ext_vector_type(4))) float f4v;    // MFMA accum / float4
typedef __attribute__((ext_vector_type(2))) float f2v;    // packed-f32 pair
typedef __hip_bfloat16 bf16;

__device__ __forceinline__ short f2bfs(float x) {
    return __builtin_bit_cast(short, __float2bfloat16(x));
}
__device__ __forceinline__ float blo(unsigned u) {
    return __builtin_bit_cast(float, u << 16);
}
__device__ __forceinline__ float bhi(unsigned u) {
    return __builtin_bit_cast(float, u & 0xffff0000u);
}
__device__ __forceinline__ f2v up2(unsigned u) {
    f2v r;
    r.x = blo(u);
    r.y = bhi(u);
    return r;
}
__device__ __forceinline__ unsigned packbf(float lo, float hi) {
    unsigned a = (unsigned)(unsigned short)f2bfs(lo);
    unsigned b = (unsigned)(unsigned short)f2bfs(hi);
    return a | (b << 16);
}

// ===========================================================================
// repack_wts: blocks [0, NRB3): NCHW ref/dist -> bf16 NHWC packed + fused
// diff, 32-px strips, 256 threads. blocks [NRB3, ...): weight repacks.
// ===========================================================================
__global__ __launch_bounds__(256) void repack_wts_kernel(
        const float* __restrict__ ref,
        const float* __restrict__ dist,
        unsigned int* __restrict__ packed,    // [NPIX][96] bf16-pairs
        float* __restrict__ out_diff,
        const float* __restrict__ dw,
        const float* __restrict__ ow,
        bf16* __restrict__ wtb,
        bf16* __restrict__ wtb2) {
    __shared__ unsigned lds[96][33];          // 12672 B, odd stride

    int tid = threadIdx.x;

    if (blockIdx.x >= NRB3) {
        // ---- weight repack part ----
        int e = (int)(blockIdx.x - NRB3) * 256 + tid;
        if (e < NWTB) {
            int j = e & 7;
            int L = (e >> 3) & 63;
            int mt = (e >> 9) & 3;
            int rest = e >> 11;
            int kc = rest % 6;
            int tap = rest / 6;
            int o = mt * 16 + (L & 15);
            int c = kc * 32 + (L >> 4) * 8 + j;
            wtb[e] = __float2bfloat16(dw[((size_t)o * C3 + c) * 9 + tap]);
        } else if (e < NWTB + NWTB2) {
            int e2 = e - NWTB;
            int j = e2 & 7;
            int L = (e2 >> 3) & 63;
            int mt = (e2 >> 9) & 1;
            int kc2 = e2 >> 10;           // 0..17 = t*2+kc
            int v = mt * 16 + (L & 15);
            int k = kc2 * 32 + ((L >> 4) & 3) * 8 + j;
            int c = k & 63;
            int tap = k >> 6;
            float val = (v < 18) ? ow[((size_t)v * Cn + c) * 9 + tap] : 0.f;
            wtb2[e2] = __float2bfloat16(val);
        }
        return;
    }

    // ---- repack part: 32-px strip ----
    int blk = blockIdx.x;
    int b = blk / (HW / 32);
    int pb = (blk - b * (HW / 32)) * 32;
    int pxg = tid & 7;                        // 8 px-quads of 4
    int chp = tid >> 3;                       // channel pair 0..31

    size_t base0 = ((size_t)(b * Cn + 2 * chp)) * HW + pb + pxg * 4;
    size_t base1 = base0 + HW;

    f4v r0 = *(const f4v*)(ref + base0);
    f4v r1 = *(const f4v*)(ref + base1);
    f4v d0 = *(const f4v*)(dist + base0);
    f4v d1 = *(const f4v*)(dist + base1);

    f4v q0 = (r0 - d0) * (r0 - d0);
    f4v q1 = (r1 - d1) * (r1 - d1);
    *(f4v*)(out_diff + base0) = q0;
    *(f4v*)(out_diff + base1) = q1;

#pragma unroll
    for (int j = 0; j < 4; ++j) {
        int p = pxg * 4 + j;
        lds[chp][p]      = packbf(r0[j], r1[j]);
        lds[32 + chp][p] = packbf(d0[j], d1[j]);
        lds[64 + chp][p] = packbf(q0[j], q1[j]);
    }
    __syncthreads();

    unsigned* pko = packed + (size_t)(b * HW + pb) * 96;
#pragma unroll
    for (int k = 0; k < 12; ++k) {
        int i = tid + k * 256;
        int p = i / 96;
        int cp = i - p * 96;
        pko[p * 96 + cp] = lds[cp][p];
    }
}

// ===========================================================================
// fused_mfma: stage 5x21 px halo in TWO channel halves (c0..95, c96..191).
// Half 0: offset conv (Phase A, pure-LDS) + deform kc 0..2 (pass 0).
// Restage half 1: deform kc 3..5 (pass 1). LDS 31.7 KB -> 5 blocks/CU.
// Bilinear vectorized as f2v (v_pk_fma_f32).
// ===========================================================================
struct Ctx {
    int o00, o01, o10, o11;      // global byte offsets (fallback path)
    int l00, l01, l10, l11;      // LDS byte offsets (fast path)
    float W00, W01, W10, W11;
    int inh;                     // all 4 corners inside staged halo
};

__device__ __forceinline__ Ctx mkctx(int t, int y, int x, int xb, float2 o2) {
    Ctx c;
    float py = (float)(y - 1 + t / 3) + o2.x;
    float pxs = (float)(x - 1 + t % 3) + o2.y;
    float fy = floorf(py), fx = floorf(pxs);
    int y0 = (int)fy, x0 = (int)fx;
    int y1 = y0 + 1, x1 = x0 + 1;
    float ay = py - fy, ax = pxs - fx;
    bool vy0 = (unsigned)y0 < (unsigned)Hd;
    bool vy1 = (unsigned)y1 < (unsigned)Hd;
    bool vx0 = (unsigned)x0 < (unsigned)Wd;
    bool vx1 = (unsigned)x1 < (unsigned)Wd;
    c.W00 = (vy0 && vx0) ? (1.f - ay) * (1.f - ax) : 0.f;
    c.W01 = (vy0 && vx1) ? (1.f - ay) * ax : 0.f;
    c.W10 = (vy1 && vx0) ? ay * (1.f - ax) : 0.f;
    c.W11 = (vy1 && vx1) ? ay * ax : 0.f;
    int y0c = min(max(y0, 0), Hd - 1), y1c = min(max(y1, 0), Hd - 1);
    int x0c = min(max(x0, 0), Wd - 1), x1c = min(max(x1, 0), Wd - 1);
    c.o00 = (y0c * Wd + x0c) * (C3 * 2);
    c.o01 = (y0c * Wd + x1c) * (C3 * 2);
    c.o10 = (y1c * Wd + x0c) * (C3 * 2);
    c.o11 = (y1c * Wd + x1c) * (C3 * 2);
    int iy0 = y0c - y + 2, iy1 = y1c - y + 2;
    int ix0 = x0c - xb + 3, ix1 = x1c - xb + 3;
    c.inh = ((unsigned)iy0 < (unsigned)HR) & ((unsigned)iy1 < (unsigned)HR) &
            ((unsigned)ix0 < (unsigned)HC) & ((unsigned)ix1 < (unsigned)HC);
    c.l00 = (iy0 * HC + ix0) * HPITCH;
    c.l01 = (iy0 * HC + ix1) * HPITCH;
    c.l10 = (iy1 * HC + ix0) * HPITCH;
    c.l11 = (iy1 * HC + ix1) * HPITCH;
    return c;
}

__device__ __forceinline__ void bilin_mfma(const s8v* rw, const Ctx& cc,
        const s8v* __restrict__ Ap, int t, int kb, int L, f4v* acc) {
#pragma unroll
    for (int i = 0; i < 3; ++i) {
        int kc = kb + i;
        u4v u00 = __builtin_bit_cast(u4v, rw[0 * 3 + i]);
        u4v u01 = __builtin_bit_cast(u4v, rw[1 * 3 + i]);
        u4v u10 = __builtin_bit_cast(u4v, rw[2 * 3 + i]);
        u4v u11 = __builtin_bit_cast(u4v, rw[3 * 3 + i]);
        u4v bu;
#pragma unroll
        for (int p = 0; p < 4; ++p) {
            f2v v = up2(u00[p]) * cc.W00;
            v += up2(u01[p]) * cc.W01;
            v += up2(u10[p]) * cc.W10;
            v += up2(u11[p]) * cc.W11;
            bu[p] = packbf(v.x, v.y);
        }
        s8v bfrag = __builtin_bit_cast(s8v, bu);
#pragma unroll
        for (int mt = 0; mt < 4; ++mt) {
            s8v a = Ap[((t * 6 + kc) * 4 + mt) * 64 + L];
            acc[mt] = __builtin_amdgcn_mfma_f32_16x16x32_bf16(a, bfrag, acc[mt], 0, 0, 0);
        }
    }
}

__global__ __launch_bounds__(192) void fused_mfma(
        const bf16* __restrict__ packed,
        const bf16* __restrict__ wtb2,
        const float* __restrict__ ob,
        const bf16* __restrict__ wtb,
        const float* __restrict__ db,
        float* __restrict__ out) {
    __shared__ f4v halo[NPR * (HPITCH / 16)];   // 21840 B (one channel-half)
    __shared__ float red[2][64 * 17];           // 8704 B (shared by phases)
    __shared__ float off_lds[16][18];           // 1152 B

    int tid = threadIdx.x;
    int L = tid & 63;
    int wv = tid / 64;                        // 0..2
    int px = L & 15;
    int lg = L >> 4;
    int blk = blockIdx.x;
    int region = (blk & 7) * 288 + (blk >> 3);        // 2304 blocks, XCD swizzle
    int p0 = region * 16;
    int b = p0 / HW;
    int pb = p0 - b * HW;
    int yb = pb / Wd;
    int xb = pb - yb * Wd;                    // strip: row yb, cols xb..xb+15
    int x = xb + px, y = yb;
    int tbase = wv * 3;

    const char* pkb = (const char*)packed + (size_t)b * HW * (C3 * 2);
    const char* hb = (const char*)halo;

    // -------- stage halo, channel half 0 (c0..95; 192 B/px, coalesced) -----
#pragma unroll 1
    for (int i = tid; i < NPR * 12; i += 192) {
        int pr = i / 12;
        int ck = i - pr * 12;
        int iy = pr / HC, ix = pr - iy * HC;
        int gy = min(max(yb - 2 + iy, 0), Hd - 1);
        int gx = min(max(xb - 3 + ix, 0), Wd - 1);
        halo[pr * (HPITCH / 16) + ck] =
            *(const f4v*)(pkb + ((size_t)(gy * Wd + gx)) * (C3 * 2) + ck * 16);
    }
    __syncthreads();

    // ---------------- Phase A: offset conv (ref = c0..63, in half 0) -------
    {
        const s8v* Ap = (const s8v*)wtb2;
        f4v acc0 = {0.f, 0.f, 0.f, 0.f};
        f4v acc1 = {0.f, 0.f, 0.f, 0.f};
#pragma unroll
        for (int tt = 0; tt < 3; ++tt) {
            int t = tbase + tt;
            int ty = t / 3, tx = t - ty * 3;
            int yy = y - 1 + ty, xx = x - 1 + tx;
            bool val = (unsigned)yy < (unsigned)Hd && (unsigned)xx < (unsigned)Wd;
            short m = val ? (short)-1 : (short)0;
            int lofs = ((1 + ty) * HC + (px + 2 + tx)) * HPITCH + lg * 16;
#pragma unroll
            for (int kc = 0; kc < 2; ++kc) {
                s8v bfrag = *(const s8v*)(hb + lofs + kc * 64) & m;
                s8v a0 = Ap[((t * 2 + kc) * 2 + 0) * 64 + L];
                s8v a1 = Ap[((t * 2 + kc) * 2 + 1) * 64 + L];
                acc0 = __builtin_amdgcn_mfma_f32_16x16x32_bf16(a0, bfrag, acc0, 0, 0, 0);
                acc1 = __builtin_amdgcn_mfma_f32_16x16x32_bf16(a1, bfrag, acc1, 0, 0, 0);
            }
        }
        if (wv != 0) {
            float* r = red[wv - 1] + L * 9;
#pragma unroll
            for (int i = 0; i < 4; ++i) r[i] = acc0[i];
#pragma unroll
            for (int i = 0; i < 4; ++i) r[4 + i] = acc1[i];
        }
        __syncthreads();
        if (wv == 0) {
            const float* r0 = red[0] + L * 9;
            const float* r1 = red[1] + L * 9;
#pragma unroll
            for (int r = 0; r < 4; ++r) {
                int v = lg * 4 + r;
                off_lds[px][v] = acc0[r] + r0[r] + r1[r] + ob[v];
            }
            if (lg == 0) {
#pragma unroll
                for (int r = 0; r < 2; ++r)
                    off_lds[px][16 + r] = acc1[r] + r0[4 + r] + r1[4 + r] + ob[16 + r];
            }
        }
        __syncthreads();
    }

    // ---------------- Phase B: deform conv, 2 channel-half passes ----------
    const s8v* Ap = (const s8v*)wtb;

    Ctx ctx[3];
    int ok = 1;
#pragma unroll
    for (int tt = 0; tt < 3; ++tt) {
        int t = tbase + tt;
        float2 o2 = {off_lds[px][2 * t], off_lds[px][2 * t + 1]};
        ctx[tt] = mkctx(t, y, x, xb, o2);
        ok &= ctx[tt].inh;
    }
    int fast = __all(ok);

    f4v acc[4];
    acc[0] = acc[1] = acc[2] = acc[3] = (f4v){0.f, 0.f, 0.f, 0.f};

    // ---- pass 0: kc 0..2 from half 0 ----
    if (fast) {
#pragma unroll
        for (int tt = 0; tt < 3; ++tt) {
            const Ctx cc = ctx[tt];
            s8v rw[12];
#pragma unroll
            for (int i = 0; i < 3; ++i) {
                int co = (i * 4 + lg) * 16;
                rw[0 * 3 + i] = *(const s8v*)(hb + cc.l00 + co);
                rw[1 * 3 + i] = *(const s8v*)(hb + cc.l01 + co);
                rw[2 * 3 + i] = *(const s8v*)(hb + cc.l10 + co);
                rw[3 * 3 + i] = *(const s8v*)(hb + cc.l11 + co);
            }
            bilin_mfma(rw, cc, Ap, tbase + tt, 0, L, acc);
        }
    } else {
#pragma unroll
        for (int tt = 0; tt < 3; ++tt) {
            const Ctx cc = ctx[tt];
            s8v rw[12];
#pragma unroll
            for (int i = 0; i < 3; ++i) {
                int co = ((0 + i) * 4 + lg) * 16;
                rw[0 * 3 + i] = *(const s8v*)(pkb + cc.o00 + co);
                rw[1 * 3 + i] = *(const s8v*)(pkb + cc.o01 + co);
                rw[2 * 3 + i] = *(const s8v*)(pkb + cc.o10 + co);
                rw[3 * 3 + i] = *(const s8v*)(pkb + cc.o11 + co);
            }
            bilin_mfma(rw, cc, Ap, tbase + tt, 0, L, acc);
        }
    }
    __syncthreads();      // all waves done reading half 0

    // -------- restage halo, channel half 1 (c96..191) ----------------------
#pragma unroll 1
    for (int i = tid; i < NPR * 12; i += 192) {
        int pr = i / 12;
        int ck = i - pr * 12;
        int iy = pr / HC, ix = pr - iy * HC;
        int gy = min(max(yb - 2 + iy, 0), Hd - 1);
        int gx = min(max(xb - 3 + ix, 0), Wd - 1);
        halo[pr * (HPITCH / 16) + ck] =
            *(const f4v*)(pkb + ((size_t)(gy * Wd + gx)) * (C3 * 2) + 192 + ck * 16);
    }
    __syncthreads();

    // ---- pass 1: kc 3..5 from half 1 ----
    if (fast) {
#pragma unroll
        for (int tt = 0; tt < 3; ++tt) {
            const Ctx cc = ctx[tt];
            s8v rw[12];
#pragma unroll
            for (int i = 0; i < 3; ++i) {
                int co = (i * 4 + lg) * 16;       // half-local channel block
                rw[0 * 3 + i] = *(const s8v*)(hb + cc.l00 + co);
                rw[1 * 3 + i] = *(const s8v*)(hb + cc.l01 + co);
                rw[2 * 3 + i] = *(const s8v*)(hb + cc.l10 + co);
                rw[3 * 3 + i] = *(const s8v*)(hb + cc.l11 + co);
            }
            bilin_mfma(rw, cc, Ap, tbase + tt, 3, L, acc);
        }
    } else {
#pragma unroll
        for (int tt = 0; tt < 3; ++tt) {
            const Ctx cc = ctx[tt];
            s8v rw[12];
#pragma unroll
            for (int i = 0; i < 3; ++i) {
                int co = ((3 + i) * 4 + lg) * 16;
                rw[0 * 3 + i] = *(const s8v*)(pkb + cc.o00 + co);
                rw[1 * 3 + i] = *(const s8v*)(pkb + cc.o01 + co);
                rw[2 * 3 + i] = *(const s8v*)(pkb + cc.o10 + co);
                rw[3 * 3 + i] = *(const s8v*)(pkb + cc.o11 + co);
            }
            bilin_mfma(rw, cc, Ap, tbase + tt, 3, L, acc);
        }
    }

    // LDS reduction: waves 1,2 deposit 16 partials/lane; wave 0 sums+stores.
    if (wv != 0) {
        float* r = red[wv - 1] + L * 17;
#pragma unroll
        for (int mt = 0; mt < 4; ++mt)
#pragma unroll
            for (int q = 0; q < 4; ++q)
                r[mt * 4 + q] = acc[mt][q];
    }
    __syncthreads();
    if (wv == 0) {
        const float* r0 = red[0] + L * 17;
        const float* r1 = red[1] + L * 17;
#pragma unroll
        for (int mt = 0; mt < 4; ++mt) {
#pragma unroll
            for (int q = 0; q < 4; ++q) {
                int o = mt * 16 + lg * 4 + q;
                float v = acc[mt][q] + r0[mt * 4 + q] + r1[mt * 4 + q] + db[o];
                out[((size_t)(b * On + o)) * HW + pb + px] = fmaxf(v, 0.f);
            }
        }
    }
}

// ---------------------------------------------------------------------------
extern "C" void kernel_launch(void* const* d_in, const int* in_sizes, int n_in,
                              void* d_out, int out_size, void* d_ws, size_t ws_size,
                              hipStream_t stream) {
    const float* ref  = (const float*)d_in[0];
    const float* dist = (const float*)d_in[1];
    const float* ow   = (const float*)d_in[2];
    const float* ob   = (const float*)d_in[3];
    const float* dw   = (const float*)d_in[4];
    const float* db   = (const float*)d_in[5];

    float* out = (float*)d_out;               // [feat | diff], each NFEAT f32

    // ws: wtb bf16 | wtb2 bf16 | packed bf16 [NPIX][192]
    bf16* ws_wtb  = (bf16*)d_ws;
    bf16* ws_wtb2 = ws_wtb + NWTB;
    bf16* ws_pk   = ws_wtb2 + NWTB2;

    int wts_blocks = (NWTB + NWTB2 + 255) / 256;      // 504
    repack_wts_kernel<<<NRB3 + wts_blocks, 256, 0, stream>>>(
        ref, dist, (unsigned int*)ws_pk, out + NFEAT, dw, ow, ws_wtb, ws_wtb2);
    fused_mfma<<<NPIX / 16, 192, 0, stream>>>(
        ws_pk, ws_wtb2, ob, ws_wtb, db, out);
}

// Round 6
// 120.668 us; speedup vs baseline: 1.1346x; 1.1346x over previous
//
#include <hip/hip_runtime.h>
#include <hip/hip_fp16.h>

// Problem constants
#define Wd    96
#define Hd    96
#define HW    9216           // 96*96
#define Bn    4
#define Cn    64             // channels per section
#define C3    192            // 3*Cn
#define On    64             // out channels
#define NPIX  (Bn*HW)        // 36864
#define NFEAT (Bn*Cn*HW)     // 2359296 elements per output tensor
#define NWTB  (9*6*4*512)    // 110592 f16 frag-linear deform weights
#define NWTB2 (18*2*64*8)    // 18432 f16 frag-linear offset weights
#define NRB3  (Bn*(HW/32))   // 1152 repack blocks (32-px strips)

// Halo geometry (16-px strip, one image row), single-stage (R4 structure)
#define HR    5              // staged rows: yb-2 .. yb+2
#define HC    21             // staged cols: xb-3 .. xb+17
#define HPITCH 400           // bytes per staged pixel (384 + 16 pad)
#define NPR   (HR*HC)        // 105 staged pixel rows

typedef __attribute__((ext_vector_type(8))) short s8v;       // 8 f16 (raw bits)
typedef __attribute__((ext_vector_type(8))) _Float16 h8v;    // 8 f16 (MFMA operand)
typedef __attribute__((ext_vector_type(4))) unsigned int u4v;
typedef __attribute__((ext_vector_type(4))) float f4v;       // MFMA accum / float4

__device__ __forceinline__ unsigned packh(float lo, float hi) {
    __half2 h = __floats2half2_rn(lo, hi);
    return __builtin_bit_cast(unsigned, h);
}

// ===========================================================================
// repack_wts: blocks [0, NRB3): NCHW ref/dist -> f16 NHWC packed + fused
// diff, 32-px strips, 256 threads. blocks [NRB3, ...): weight repacks (f16).
// ===========================================================================
__global__ __launch_bounds__(256) void repack_wts_kernel(
        const float* __restrict__ ref,
        const float* __restrict__ dist,
        unsigned int* __restrict__ packed,    // [NPIX][96] f16-pairs
        float* __restrict__ out_diff,
        const float* __restrict__ dw,
        const float* __restrict__ ow,
        __half* __restrict__ wtb,
        __half* __restrict__ wtb2) {
    __shared__ unsigned lds[96][33];          // 12672 B, odd stride

    int tid = threadIdx.x;

    if (blockIdx.x >= NRB3) {
        // ---- weight repack part ----
        int e = (int)(blockIdx.x - NRB3) * 256 + tid;
        if (e < NWTB) {
            int j = e & 7;
            int L = (e >> 3) & 63;
            int mt = (e >> 9) & 3;
            int rest = e >> 11;
            int kc = rest % 6;
            int tap = rest / 6;
            int o = mt * 16 + (L & 15);
            int c = kc * 32 + (L >> 4) * 8 + j;
            wtb[e] = __float2half(dw[((size_t)o * C3 + c) * 9 + tap]);
        } else if (e < NWTB + NWTB2) {
            int e2 = e - NWTB;
            int j = e2 & 7;
            int L = (e2 >> 3) & 63;
            int mt = (e2 >> 9) & 1;
            int kc2 = e2 >> 10;           // 0..17 = t*2+kc
            int v = mt * 16 + (L & 15);
            int k = kc2 * 32 + ((L >> 4) & 3) * 8 + j;
            int c = k & 63;
            int tap = k >> 6;
            float val = (v < 18) ? ow[((size_t)v * Cn + c) * 9 + tap] : 0.f;
            wtb2[e2] = __float2half(val);
        }
        return;
    }

    // ---- repack part: 32-px strip ----
    int blk = blockIdx.x;
    int b = blk / (HW / 32);
    int pb = (blk - b * (HW / 32)) * 32;
    int pxg = tid & 7;                        // 8 px-quads of 4
    int chp = tid >> 3;                       // channel pair 0..31

    size_t base0 = ((size_t)(b * Cn + 2 * chp)) * HW + pb + pxg * 4;
    size_t base1 = base0 + HW;

    f4v r0 = *(const f4v*)(ref + base0);
    f4v r1 = *(const f4v*)(ref + base1);
    f4v d0 = *(const f4v*)(dist + base0);
    f4v d1 = *(const f4v*)(dist + base1);

    f4v q0 = (r0 - d0) * (r0 - d0);
    f4v q1 = (r1 - d1) * (r1 - d1);
    *(f4v*)(out_diff + base0) = q0;
    *(f4v*)(out_diff + base1) = q1;

#pragma unroll
    for (int j = 0; j < 4; ++j) {
        int p = pxg * 4 + j;
        lds[chp][p]      = packh(r0[j], r1[j]);
        lds[32 + chp][p] = packh(d0[j], d1[j]);
        lds[64 + chp][p] = packh(q0[j], q1[j]);
    }
    __syncthreads();

    unsigned* pko = packed + (size_t)(b * HW + pb) * 96;
#pragma unroll
    for (int k = 0; k < 12; ++k) {
        int i = tid + k * 256;
        int p = i / 96;
        int cp = i - p * 96;
        pko[p * 96 + cp] = lds[cp][p];
    }
}

// ===========================================================================
// fused_mfma: single-stage 5x21 px halo (42 KB, R4 structure), f16 pipeline.
// Phase A: offset conv (pure-LDS). Phase B: deform conv with bilinear blend
// done DIRECTLY on packed f16 pairs via v_pk_fma_f16 (4 VALU/word vs ~16).
// ===========================================================================
struct Ctx {
    int o00, o01, o10, o11;      // global byte offsets (fallback path)
    int l00, l01, l10, l11;      // LDS byte offsets (fast path)
    float W00, W01, W10, W11;
    int inh;                     // all 4 corners inside staged halo
};

__device__ __forceinline__ Ctx mkctx(int t, int y, int x, int xb, float2 o2) {
    Ctx c;
    float py = (float)(y - 1 + t / 3) + o2.x;
    float pxs = (float)(x - 1 + t % 3) + o2.y;
    float fy = floorf(py), fx = floorf(pxs);
    int y0 = (int)fy, x0 = (int)fx;
    int y1 = y0 + 1, x1 = x0 + 1;
    float ay = py - fy, ax = pxs - fx;
    bool vy0 = (unsigned)y0 < (unsigned)Hd;
    bool vy1 = (unsigned)y1 < (unsigned)Hd;
    bool vx0 = (unsigned)x0 < (unsigned)Wd;
    bool vx1 = (unsigned)x1 < (unsigned)Wd;
    c.W00 = (vy0 && vx0) ? (1.f - ay) * (1.f - ax) : 0.f;
    c.W01 = (vy0 && vx1) ? (1.f - ay) * ax : 0.f;
    c.W10 = (vy1 && vx0) ? ay * (1.f - ax) : 0.f;
    c.W11 = (vy1 && vx1) ? ay * ax : 0.f;
    int y0c = min(max(y0, 0), Hd - 1), y1c = min(max(y1, 0), Hd - 1);
    int x0c = min(max(x0, 0), Wd - 1), x1c = min(max(x1, 0), Wd - 1);
    c.o00 = (y0c * Wd + x0c) * (C3 * 2);
    c.o01 = (y0c * Wd + x1c) * (C3 * 2);
    c.o10 = (y1c * Wd + x0c) * (C3 * 2);
    c.o11 = (y1c * Wd + x1c) * (C3 * 2);
    int iy0 = y0c - y + 2, iy1 = y1c - y + 2;
    int ix0 = x0c - xb + 3, ix1 = x1c - xb + 3;
    c.inh = ((unsigned)iy0 < (unsigned)HR) & ((unsigned)iy1 < (unsigned)HR) &
            ((unsigned)ix0 < (unsigned)HC) & ((unsigned)ix1 < (unsigned)HC);
    c.l00 = (iy0 * HC + ix0) * HPITCH;
    c.l01 = (iy0 * HC + ix1) * HPITCH;
    c.l10 = (iy1 * HC + ix0) * HPITCH;
    c.l11 = (iy1 * HC + ix1) * HPITCH;
    return c;
}

__device__ __forceinline__ __half2 uh2(unsigned u) {
    return __builtin_bit_cast(__half2, u);
}

// Bilinear blend on packed f16 pairs + 4 MFMAs, for one (tap, kc-triple).
__device__ __forceinline__ void bilin_mfma(const s8v* rw, const Ctx& cc,
        const s8v* __restrict__ Ap, int t, int kb, int L, f4v* acc) {
    __half2 w00 = __float2half2_rn(cc.W00);
    __half2 w01 = __float2half2_rn(cc.W01);
    __half2 w10 = __float2half2_rn(cc.W10);
    __half2 w11 = __float2half2_rn(cc.W11);
#pragma unroll
    for (int i = 0; i < 3; ++i) {
        int kc = kb + i;
        u4v u00 = __builtin_bit_cast(u4v, rw[0 * 3 + i]);
        u4v u01 = __builtin_bit_cast(u4v, rw[1 * 3 + i]);
        u4v u10 = __builtin_bit_cast(u4v, rw[2 * 3 + i]);
        u4v u11 = __builtin_bit_cast(u4v, rw[3 * 3 + i]);
        u4v bu;
#pragma unroll
        for (int p = 0; p < 4; ++p) {
            __half2 v = __hmul2(uh2(u00[p]), w00);
            v = __hfma2(uh2(u01[p]), w01, v);
            v = __hfma2(uh2(u10[p]), w10, v);
            v = __hfma2(uh2(u11[p]), w11, v);
            bu[p] = __builtin_bit_cast(unsigned, v);
        }
        h8v bfrag = __builtin_bit_cast(h8v, bu);
#pragma unroll
        for (int mt = 0; mt < 4; ++mt) {
            h8v a = __builtin_bit_cast(h8v, Ap[((t * 6 + kc) * 4 + mt) * 64 + L]);
            acc[mt] = __builtin_amdgcn_mfma_f32_16x16x32_f16(a, bfrag, acc[mt], 0, 0, 0);
        }
    }
}

__global__ __launch_bounds__(192) void fused_mfma(
        const __half* __restrict__ packed,
        const __half* __restrict__ wtb2,
        const float* __restrict__ ob,
        const __half* __restrict__ wtb,
        const float* __restrict__ db,
        float* __restrict__ out) {
    __shared__ f4v halo[NPR * (HPITCH / 16)];   // 42000 B
    __shared__ float red[2][64 * 17];           // 8704 B (shared by phases)
    __shared__ float off_lds[16][18];           // 1152 B

    int tid = threadIdx.x;
    int L = tid & 63;
    int wv = tid / 64;                        // 0..2
    int px = L & 15;
    int lg = L >> 4;
    int blk = blockIdx.x;
    int region = (blk & 7) * 288 + (blk >> 3);        // 2304 blocks, XCD swizzle
    int p0 = region * 16;
    int b = p0 / HW;
    int pb = p0 - b * HW;
    int yb = pb / Wd;
    int xb = pb - yb * Wd;                    // strip: row yb, cols xb..xb+15
    int x = xb + px, y = yb;
    int tbase = wv * 3;

    const char* pkb = (const char*)packed + (size_t)b * HW * (C3 * 2);
    const char* hb = (const char*)halo;

    // ---------------- stage halo (coalesced: 5 contiguous 8.4KB row-spans) --
#pragma unroll 1
    for (int i = tid; i < NPR * 24; i += 192) {
        int pr = i / 24;
        int ck = i - pr * 24;
        int iy = pr / HC, ix = pr - iy * HC;
        int gy = min(max(yb - 2 + iy, 0), Hd - 1);
        int gx = min(max(xb - 3 + ix, 0), Wd - 1);
        halo[pr * (HPITCH / 16) + ck] =
            *(const f4v*)(pkb + ((size_t)(gy * Wd + gx)) * (C3 * 2) + ck * 16);
    }
    __syncthreads();

    // ---------------- Phase A: offset conv (ref = c0..63) ------------------
    {
        const s8v* Ap = (const s8v*)wtb2;
        f4v acc0 = {0.f, 0.f, 0.f, 0.f};
        f4v acc1 = {0.f, 0.f, 0.f, 0.f};
#pragma unroll
        for (int tt = 0; tt < 3; ++tt) {
            int t = tbase + tt;
            int ty = t / 3, tx = t - ty * 3;
            int yy = y - 1 + ty, xx = x - 1 + tx;
            bool val = (unsigned)yy < (unsigned)Hd && (unsigned)xx < (unsigned)Wd;
            short m = val ? (short)-1 : (short)0;
            int lofs = ((1 + ty) * HC + (px + 2 + tx)) * HPITCH + lg * 16;
#pragma unroll
            for (int kc = 0; kc < 2; ++kc) {
                s8v braw = *(const s8v*)(hb + lofs + kc * 64) & m;
                h8v bfrag = __builtin_bit_cast(h8v, braw);
                h8v a0 = __builtin_bit_cast(h8v, Ap[((t * 2 + kc) * 2 + 0) * 64 + L]);
                h8v a1 = __builtin_bit_cast(h8v, Ap[((t * 2 + kc) * 2 + 1) * 64 + L]);
                acc0 = __builtin_amdgcn_mfma_f32_16x16x32_f16(a0, bfrag, acc0, 0, 0, 0);
                acc1 = __builtin_amdgcn_mfma_f32_16x16x32_f16(a1, bfrag, acc1, 0, 0, 0);
            }
        }
        if (wv != 0) {
            float* r = red[wv - 1] + L * 9;
#pragma unroll
            for (int i = 0; i < 4; ++i) r[i] = acc0[i];
#pragma unroll
            for (int i = 0; i < 4; ++i) r[4 + i] = acc1[i];
        }
        __syncthreads();
        if (wv == 0) {
            const float* r0 = red[0] + L * 9;
            const float* r1 = red[1] + L * 9;
#pragma unroll
            for (int r = 0; r < 4; ++r) {
                int v = lg * 4 + r;
                off_lds[px][v] = acc0[r] + r0[r] + r1[r] + ob[v];
            }
            if (lg == 0) {
#pragma unroll
                for (int r = 0; r < 2; ++r)
                    off_lds[px][16 + r] = acc1[r] + r0[4 + r] + r1[4 + r] + ob[16 + r];
            }
        }
        __syncthreads();
    }

    // ---------------- Phase B: deform conv ----------------
    const s8v* Ap = (const s8v*)wtb;

    Ctx ctx[3];
    int ok = 1;
#pragma unroll
    for (int tt = 0; tt < 3; ++tt) {
        int t = tbase + tt;
        float2 o2 = {off_lds[px][2 * t], off_lds[px][2 * t + 1]};
        ctx[tt] = mkctx(t, y, x, xb, o2);
        ok &= ctx[tt].inh;
    }

    f4v acc[4];
    acc[0] = acc[1] = acc[2] = acc[3] = (f4v){0.f, 0.f, 0.f, 0.f};

    if (__all(ok)) {
        // fast path: bilinear gathers from LDS halo
#pragma unroll
        for (int h = 0; h < 6; ++h) {             // 3 taps x 2 halves
            int tt = h >> 1;
            int t = tbase + tt;
            int kb = (h & 1) * 3;
            const Ctx cc = ctx[tt];
            s8v rw[12];
#pragma unroll
            for (int i = 0; i < 3; ++i) {
                int co = ((kb + i) * 4 + lg) * 16;
                rw[0 * 3 + i] = *(const s8v*)(hb + cc.l00 + co);
                rw[1 * 3 + i] = *(const s8v*)(hb + cc.l01 + co);
                rw[2 * 3 + i] = *(const s8v*)(hb + cc.l10 + co);
                rw[3 * 3 + i] = *(const s8v*)(hb + cc.l11 + co);
            }
            bilin_mfma(rw, cc, Ap, t, kb, L, acc);
        }
    } else {
        // fallback: global gathers (rare; arbitrary offsets stay correct)
#pragma unroll
        for (int h = 0; h < 6; ++h) {
            int tt = h >> 1;
            int t = tbase + tt;
            int kb = (h & 1) * 3;
            const Ctx cc = ctx[tt];
            s8v rw[12];
#pragma unroll
            for (int i = 0; i < 3; ++i) {
                int co = ((kb + i) * 4 + lg) * 16;
                rw[0 * 3 + i] = *(const s8v*)(pkb + cc.o00 + co);
                rw[1 * 3 + i] = *(const s8v*)(pkb + cc.o01 + co);
                rw[2 * 3 + i] = *(const s8v*)(pkb + cc.o10 + co);
                rw[3 * 3 + i] = *(const s8v*)(pkb + cc.o11 + co);
            }
            bilin_mfma(rw, cc, Ap, t, kb, L, acc);
        }
    }

    // LDS reduction: waves 1,2 deposit 16 partials/lane; wave 0 sums+stores.
    if (wv != 0) {
        float* r = red[wv - 1] + L * 17;
#pragma unroll
        for (int mt = 0; mt < 4; ++mt)
#pragma unroll
            for (int q = 0; q < 4; ++q)
                r[mt * 4 + q] = acc[mt][q];
    }
    __syncthreads();
    if (wv == 0) {
        const float* r0 = red[0] + L * 17;
        const float* r1 = red[1] + L * 17;
#pragma unroll
        for (int mt = 0; mt < 4; ++mt) {
#pragma unroll
            for (int q = 0; q < 4; ++q) {
                int o = mt * 16 + lg * 4 + q;
                float v = acc[mt][q] + r0[mt * 4 + q] + r1[mt * 4 + q] + db[o];
                out[((size_t)(b * On + o)) * HW + pb + px] = fmaxf(v, 0.f);
            }
        }
    }
}

// ---------------------------------------------------------------------------
extern "C" void kernel_launch(void* const* d_in, const int* in_sizes, int n_in,
                              void* d_out, int out_size, void* d_ws, size_t ws_size,
                              hipStream_t stream) {
    const float* ref  = (const float*)d_in[0];
    const float* dist = (const float*)d_in[1];
    const float* ow   = (const float*)d_in[2];
    const float* ob   = (const float*)d_in[3];
    const float* dw   = (const float*)d_in[4];
    const float* db   = (const float*)d_in[5];

    float* out = (float*)d_out;               // [feat | diff], each NFEAT f32

    // ws: wtb f16 | wtb2 f16 | packed f16 [NPIX][192]
    __half* ws_wtb  = (__half*)d_ws;
    __half* ws_wtb2 = ws_wtb + NWTB;
    __half* ws_pk   = ws_wtb2 + NWTB2;

    int wts_blocks = (NWTB + NWTB2 + 255) / 256;      // 504
    repack_wts_kernel<<<NRB3 + wts_blocks, 256, 0, stream>>>(
        ref, dist, (unsigned int*)ws_pk, out + NFEAT, dw, ow, ws_wtb, ws_wtb2);
    fused_mfma<<<NPIX / 16, 192, 0, stream>>>(
        ws_pk, ws_wtb2, ob, ws_wtb, db, out);
}

// Round 7
// 119.169 us; speedup vs baseline: 1.1489x; 1.0126x over previous
//
#include <hip/hip_runtime.h>
#include <hip/hip_fp16.h>

// Problem constants
#define Wd    96
#define Hd    96
#define HW    9216           // 96*96
#define Bn    4
#define Cn    64             // channels per section
#define C3    192            // 3*Cn
#define On    64             // out channels
#define NPIX  (Bn*HW)        // 36864
#define NFEAT (Bn*Cn*HW)     // 2359296 elements per output tensor
#define NWTB  (9*6*4*512)    // 110592 f16 frag-linear deform weights
#define NWTB2 (18*2*64*8)    // 18432 f16 frag-linear offset weights
#define NRB3  (Bn*(HW/32))   // 1152 repack blocks (32-px strips)

// Halo geometry: 16x2 px tile -> rows yb-2..yb+3, cols xb-3..xb+17
#define HR2   6
#define HC    21
#define HPITCH 400           // bytes per staged pixel (384 + 16 pad)
#define NPR2  (HR2*HC)       // 126 staged pixel rows
#define SELEM (NPR2*24)      // 3024 f4v staging elements
#define HALO_B (NPR2*HPITCH) // 50400
#define REDA_B (2*2*64*9*4)  // 9216
#define NFBLK 1152           // fused blocks (6 x 48 x 4)

typedef __attribute__((ext_vector_type(8))) short s8v;       // 8 f16 (raw bits)
typedef __attribute__((ext_vector_type(8))) _Float16 h8v;    // 8 f16 (MFMA operand)
typedef __attribute__((ext_vector_type(4))) unsigned int u4v;
typedef __attribute__((ext_vector_type(4))) float f4v;       // MFMA accum / float4

__device__ __forceinline__ unsigned packh(float lo, float hi) {
    __half2 h = __floats2half2_rn(lo, hi);
    return __builtin_bit_cast(unsigned, h);
}

// ===========================================================================
// repack_wts: unchanged from R6 (f16). blocks [0, NRB3): NCHW -> f16 NHWC
// packed + fused diff. blocks [NRB3, ...): weight repacks.
// ===========================================================================
__global__ __launch_bounds__(256) void repack_wts_kernel(
        const float* __restrict__ ref,
        const float* __restrict__ dist,
        unsigned int* __restrict__ packed,    // [NPIX][96] f16-pairs
        float* __restrict__ out_diff,
        const float* __restrict__ dw,
        const float* __restrict__ ow,
        __half* __restrict__ wtb,
        __half* __restrict__ wtb2) {
    __shared__ unsigned lds[96][33];          // 12672 B, odd stride

    int tid = threadIdx.x;

    if (blockIdx.x >= NRB3) {
        int e = (int)(blockIdx.x - NRB3) * 256 + tid;
        if (e < NWTB) {
            int j = e & 7;
            int L = (e >> 3) & 63;
            int mt = (e >> 9) & 3;
            int rest = e >> 11;
            int kc = rest % 6;
            int tap = rest / 6;
            int o = mt * 16 + (L & 15);
            int c = kc * 32 + (L >> 4) * 8 + j;
            wtb[e] = __float2half(dw[((size_t)o * C3 + c) * 9 + tap]);
        } else if (e < NWTB + NWTB2) {
            int e2 = e - NWTB;
            int j = e2 & 7;
            int L = (e2 >> 3) & 63;
            int mt = (e2 >> 9) & 1;
            int kc2 = e2 >> 10;           // 0..17 = t*2+kc
            int v = mt * 16 + (L & 15);
            int k = kc2 * 32 + ((L >> 4) & 3) * 8 + j;
            int c = k & 63;
            int tap = k >> 6;
            float val = (v < 18) ? ow[((size_t)v * Cn + c) * 9 + tap] : 0.f;
            wtb2[e2] = __float2half(val);
        }
        return;
    }

    // ---- repack part: 32-px strip ----
    int blk = blockIdx.x;
    int b = blk / (HW / 32);
    int pb = (blk - b * (HW / 32)) * 32;
    int pxg = tid & 7;                        // 8 px-quads of 4
    int chp = tid >> 3;                       // channel pair 0..31

    size_t base0 = ((size_t)(b * Cn + 2 * chp)) * HW + pb + pxg * 4;
    size_t base1 = base0 + HW;

    f4v r0 = *(const f4v*)(ref + base0);
    f4v r1 = *(const f4v*)(ref + base1);
    f4v d0 = *(const f4v*)(dist + base0);
    f4v d1 = *(const f4v*)(dist + base1);

    f4v q0 = (r0 - d0) * (r0 - d0);
    f4v q1 = (r1 - d1) * (r1 - d1);
    *(f4v*)(out_diff + base0) = q0;
    *(f4v*)(out_diff + base1) = q1;

#pragma unroll
    for (int j = 0; j < 4; ++j) {
        int p = pxg * 4 + j;
        lds[chp][p]      = packh(r0[j], r1[j]);
        lds[32 + chp][p] = packh(d0[j], d1[j]);
        lds[64 + chp][p] = packh(q0[j], q1[j]);
    }
    __syncthreads();

    unsigned* pko = packed + (size_t)(b * HW + pb) * 96;
#pragma unroll
    for (int k = 0; k < 12; ++k) {
        int i = tid + k * 256;
        int p = i / 96;
        int cp = i - p * 96;
        pko[p * 96 + cp] = lds[cp][p];
    }
}

// ===========================================================================
// fused_mfma: 16x2 px tile, 384 thr = 2 row-groups x 3-way split-K.
// One 50.4 KB halo serves 32 px (1575 B/px staged vs 2625 before).
// Staging fully unrolled (8 loads in flight). Phase-B reduction buffer
// aliases the dead halo. LDS 61.9 KB -> 2 blocks/CU = 3 waves/SIMD.
// ===========================================================================
struct Ctx {
    int o00, o01, o10, o11;      // global byte offsets (fallback path)
    int l00, l01, l10, l11;      // LDS byte offsets (fast path)
    float W00, W01, W10, W11;
    int inh;                     // all 4 corners inside staged halo
};

__device__ __forceinline__ Ctx mkctx(int t, int y, int x, int xb, int yb,
                                     float2 o2) {
    Ctx c;
    float py = (float)(y - 1 + t / 3) + o2.x;
    float pxs = (float)(x - 1 + t % 3) + o2.y;
    float fy = floorf(py), fx = floorf(pxs);
    int y0 = (int)fy, x0 = (int)fx;
    int y1 = y0 + 1, x1 = x0 + 1;
    float ay = py - fy, ax = pxs - fx;
    bool vy0 = (unsigned)y0 < (unsigned)Hd;
    bool vy1 = (unsigned)y1 < (unsigned)Hd;
    bool vx0 = (unsigned)x0 < (unsigned)Wd;
    bool vx1 = (unsigned)x1 < (unsigned)Wd;
    c.W00 = (vy0 && vx0) ? (1.f - ay) * (1.f - ax) : 0.f;
    c.W01 = (vy0 && vx1) ? (1.f - ay) * ax : 0.f;
    c.W10 = (vy1 && vx0) ? ay * (1.f - ax) : 0.f;
    c.W11 = (vy1 && vx1) ? ay * ax : 0.f;
    int y0c = min(max(y0, 0), Hd - 1), y1c = min(max(y1, 0), Hd - 1);
    int x0c = min(max(x0, 0), Wd - 1), x1c = min(max(x1, 0), Wd - 1);
    c.o00 = (y0c * Wd + x0c) * (C3 * 2);
    c.o01 = (y0c * Wd + x1c) * (C3 * 2);
    c.o10 = (y1c * Wd + x0c) * (C3 * 2);
    c.o11 = (y1c * Wd + x1c) * (C3 * 2);
    int iy0 = y0c - yb + 2, iy1 = y1c - yb + 2;      // halo row 0 = yb-2
    int ix0 = x0c - xb + 3, ix1 = x1c - xb + 3;
    c.inh = ((unsigned)iy0 < (unsigned)HR2) & ((unsigned)iy1 < (unsigned)HR2) &
            ((unsigned)ix0 < (unsigned)HC) & ((unsigned)ix1 < (unsigned)HC);
    c.l00 = (iy0 * HC + ix0) * HPITCH;
    c.l01 = (iy0 * HC + ix1) * HPITCH;
    c.l10 = (iy1 * HC + ix0) * HPITCH;
    c.l11 = (iy1 * HC + ix1) * HPITCH;
    return c;
}

__device__ __forceinline__ __half2 uh2(unsigned u) {
    return __builtin_bit_cast(__half2, u);
}

// Bilinear blend on packed f16 pairs + 4 MFMAs, for one (tap, kc-triple).
__device__ __forceinline__ void bilin_mfma(const s8v* rw, const Ctx& cc,
        const s8v* __restrict__ Ap, int t, int kb, int L, f4v* acc) {
    __half2 w00 = __float2half2_rn(cc.W00);
    __half2 w01 = __float2half2_rn(cc.W01);
    __half2 w10 = __float2half2_rn(cc.W10);
    __half2 w11 = __float2half2_rn(cc.W11);
#pragma unroll
    for (int i = 0; i < 3; ++i) {
        int kc = kb + i;
        u4v u00 = __builtin_bit_cast(u4v, rw[0 * 3 + i]);
        u4v u01 = __builtin_bit_cast(u4v, rw[1 * 3 + i]);
        u4v u10 = __builtin_bit_cast(u4v, rw[2 * 3 + i]);
        u4v u11 = __builtin_bit_cast(u4v, rw[3 * 3 + i]);
        u4v bu;
#pragma unroll
        for (int p = 0; p < 4; ++p) {
            __half2 v = __hmul2(uh2(u00[p]), w00);
            v = __hfma2(uh2(u01[p]), w01, v);
            v = __hfma2(uh2(u10[p]), w10, v);
            v = __hfma2(uh2(u11[p]), w11, v);
            bu[p] = __builtin_bit_cast(unsigned, v);
        }
        h8v bfrag = __builtin_bit_cast(h8v, bu);
#pragma unroll
        for (int mt = 0; mt < 4; ++mt) {
            h8v a = __builtin_bit_cast(h8v, Ap[((t * 6 + kc) * 4 + mt) * 64 + L]);
            acc[mt] = __builtin_amdgcn_mfma_f32_16x16x32_f16(a, bfrag, acc[mt], 0, 0, 0);
        }
    }
}

__global__ __launch_bounds__(384, 3) void fused_mfma(
        const __half* __restrict__ packed,
        const __half* __restrict__ wtb2,
        const float* __restrict__ ob,
        const __half* __restrict__ wtb,
        const float* __restrict__ db,
        float* __restrict__ out) {
    __shared__ __align__(16) char smem[HALO_B + REDA_B + 2 * 16 * 18 * 4];
    f4v* halo = (f4v*)smem;                               // 50400 B
    float* redA = (float*)(smem + HALO_B);                // 9216 B
    float (*off_l)[18] = (float(*)[18])(smem + HALO_B + REDA_B);  // [32][18]
    float* redB = (float*)smem;                           // aliases halo

    int tid = threadIdx.x;
    int L = tid & 63;
    int wv = tid >> 6;                        // 0..5
    int g  = wv / 3;                          // row group 0..1
    int kv = wv - g * 3;                      // split-K 0..2
    int px = L & 15;
    int lg = L >> 4;
    int blk = blockIdx.x;
    int region = (blk & 7) * 144 + (blk >> 3);        // 1152 blocks, XCD swizzle
    int b = region / 288;
    int rt = region - b * 288;
    int yt = rt / 6;
    int xt = rt - yt * 6;
    int yb = yt * 2, xb = xt * 16;            // tile: rows yb..yb+1, cols xb..+15
    int y = yb + g, x = xb + px;
    int pb = y * Wd + xb;                     // this group's output row base
    int tbase = kv * 3;

    const char* pkb = (const char*)packed + (size_t)b * HW * (C3 * 2);
    const char* hb = (const char*)halo;

    // ---------------- stage halo: 3024 f4v, fully unrolled batch -----------
    {
        f4v stg[8];
        int slot[8];
#pragma unroll
        for (int k = 0; k < 8; ++k) {
            int i = tid + k * 384;
            bool act = (k < 7) ? true : (tid < SELEM - 7 * 384);
            int pr = i / 24, ck = i - pr * 24;
            int iy = pr / HC, ix = pr - iy * HC;
            int gy = min(max(yb - 2 + iy, 0), Hd - 1);
            int gx = min(max(xb - 3 + ix, 0), Wd - 1);
            slot[k] = act ? (pr * (HPITCH / 16) + ck) : -1;
            if (act)
                stg[k] = *(const f4v*)(pkb + ((size_t)(gy * Wd + gx)) * (C3 * 2) + ck * 16);
        }
#pragma unroll
        for (int k = 0; k < 8; ++k)
            if (slot[k] >= 0) halo[slot[k]] = stg[k];
    }
    __syncthreads();

    // ---------------- Phase A: offset conv (ref = c0..63, pure-LDS) --------
    {
        const s8v* Ap = (const s8v*)wtb2;
        f4v acc0 = {0.f, 0.f, 0.f, 0.f};
        f4v acc1 = {0.f, 0.f, 0.f, 0.f};
#pragma unroll
        for (int tt = 0; tt < 3; ++tt) {
            int t = tbase + tt;
            int ty = t / 3, tx = t - ty * 3;
            int yy = y - 1 + ty, xx = x - 1 + tx;
            bool val = (unsigned)yy < (unsigned)Hd && (unsigned)xx < (unsigned)Wd;
            short m = val ? (short)-1 : (short)0;
            int lofs = ((g + 1 + ty) * HC + (px + 2 + tx)) * HPITCH + lg * 16;
#pragma unroll
            for (int kc = 0; kc < 2; ++kc) {
                s8v braw = *(const s8v*)(hb + lofs + kc * 64) & m;
                h8v bfrag = __builtin_bit_cast(h8v, braw);
                h8v a0 = __builtin_bit_cast(h8v, Ap[((t * 2 + kc) * 2 + 0) * 64 + L]);
                h8v a1 = __builtin_bit_cast(h8v, Ap[((t * 2 + kc) * 2 + 1) * 64 + L]);
                acc0 = __builtin_amdgcn_mfma_f32_16x16x32_f16(a0, bfrag, acc0, 0, 0, 0);
                acc1 = __builtin_amdgcn_mfma_f32_16x16x32_f16(a1, bfrag, acc1, 0, 0, 0);
            }
        }
        if (kv != 0) {
            float* r = redA + ((g * 2 + kv - 1) * 64 + L) * 9;
#pragma unroll
            for (int i = 0; i < 4; ++i) r[i] = acc0[i];
#pragma unroll
            for (int i = 0; i < 4; ++i) r[4 + i] = acc1[i];
        }
        __syncthreads();
        if (kv == 0) {
            const float* r0 = redA + ((g * 2 + 0) * 64 + L) * 9;
            const float* r1 = redA + ((g * 2 + 1) * 64 + L) * 9;
#pragma unroll
            for (int r = 0; r < 4; ++r) {
                int v = lg * 4 + r;
                off_l[g * 16 + px][v] = acc0[r] + r0[r] + r1[r] + ob[v];
            }
            if (lg == 0) {
#pragma unroll
                for (int r = 0; r < 2; ++r)
                    off_l[g * 16 + px][16 + r] = acc1[r] + r0[4 + r] + r1[4 + r] + ob[16 + r];
            }
        }
        __syncthreads();
    }

    // ---------------- Phase B: deform conv ----------------
    const s8v* Ap = (const s8v*)wtb;

    Ctx ctx[3];
    int ok = 1;
#pragma unroll
    for (int tt = 0; tt < 3; ++tt) {
        int t = tbase + tt;
        float2 o2 = {off_l[g * 16 + px][2 * t], off_l[g * 16 + px][2 * t + 1]};
        ctx[tt] = mkctx(t, y, x, xb, yb, o2);
        ok &= ctx[tt].inh;
    }

    f4v acc[4];
    acc[0] = acc[1] = acc[2] = acc[3] = (f4v){0.f, 0.f, 0.f, 0.f};

    if (__all(ok)) {
        // fast path: bilinear gathers from LDS halo
#pragma unroll
        for (int h = 0; h < 6; ++h) {             // 3 taps x 2 halves
            int tt = h >> 1;
            int t = tbase + tt;
            int kb = (h & 1) * 3;
            const Ctx cc = ctx[tt];
            s8v rw[12];
#pragma unroll
            for (int i = 0; i < 3; ++i) {
                int co = ((kb + i) * 4 + lg) * 16;
                rw[0 * 3 + i] = *(const s8v*)(hb + cc.l00 + co);
                rw[1 * 3 + i] = *(const s8v*)(hb + cc.l01 + co);
                rw[2 * 3 + i] = *(const s8v*)(hb + cc.l10 + co);
                rw[3 * 3 + i] = *(const s8v*)(hb + cc.l11 + co);
            }
            bilin_mfma(rw, cc, Ap, t, kb, L, acc);
        }
    } else {
        // fallback: global gathers (rare; arbitrary offsets stay correct)
#pragma unroll
        for (int h = 0; h < 6; ++h) {
            int tt = h >> 1;
            int t = tbase + tt;
            int kb = (h & 1) * 3;
            const Ctx cc = ctx[tt];
            s8v rw[12];
#pragma unroll
            for (int i = 0; i < 3; ++i) {
                int co = ((kb + i) * 4 + lg) * 16;
                rw[0 * 3 + i] = *(const s8v*)(pkb + cc.o00 + co);
                rw[1 * 3 + i] = *(const s8v*)(pkb + cc.o01 + co);
                rw[2 * 3 + i] = *(const s8v*)(pkb + cc.o10 + co);
                rw[3 * 3 + i] = *(const s8v*)(pkb + cc.o11 + co);
            }
            bilin_mfma(rw, cc, Ap, t, kb, L, acc);
        }
    }

    // -------- reduction: redB aliases halo (all halo reads done) -----------
    __syncthreads();
    if (kv != 0) {
        float* r = redB + ((g * 2 + kv - 1) * 64 + L) * 17;
#pragma unroll
        for (int mt = 0; mt < 4; ++mt)
#pragma unroll
            for (int q = 0; q < 4; ++q)
                r[mt * 4 + q] = acc[mt][q];
    }
    __syncthreads();
    if (kv == 0) {
        const float* r0 = redB + ((g * 2 + 0) * 64 + L) * 17;
        const float* r1 = redB + ((g * 2 + 1) * 64 + L) * 17;
#pragma unroll
        for (int mt = 0; mt < 4; ++mt) {
#pragma unroll
            for (int q = 0; q < 4; ++q) {
                int o = mt * 16 + lg * 4 + q;
                float v = acc[mt][q] + r0[mt * 4 + q] + r1[mt * 4 + q] + db[o];
                out[((size_t)(b * On + o)) * HW + pb + px] = fmaxf(v, 0.f);
            }
        }
    }
}

// ---------------------------------------------------------------------------
extern "C" void kernel_launch(void* const* d_in, const int* in_sizes, int n_in,
                              void* d_out, int out_size, void* d_ws, size_t ws_size,
                              hipStream_t stream) {
    const float* ref  = (const float*)d_in[0];
    const float* dist = (const float*)d_in[1];
    const float* ow   = (const float*)d_in[2];
    const float* ob   = (const float*)d_in[3];
    const float* dw   = (const float*)d_in[4];
    const float* db   = (const float*)d_in[5];

    float* out = (float*)d_out;               // [feat | diff], each NFEAT f32

    // ws: wtb f16 | wtb2 f16 | packed f16 [NPIX][192]
    __half* ws_wtb  = (__half*)d_ws;
    __half* ws_wtb2 = ws_wtb + NWTB;
    __half* ws_pk   = ws_wtb2 + NWTB2;

    int wts_blocks = (NWTB + NWTB2 + 255) / 256;      // 504
    repack_wts_kernel<<<NRB3 + wts_blocks, 256, 0, stream>>>(
        ref, dist, (unsigned int*)ws_pk, out + NFEAT, dw, ow, ws_wtb, ws_wtb2);
    fused_mfma<<<NFBLK, 384, 0, stream>>>(
        ws_pk, ws_wtb2, ob, ws_wtb, db, out);
}

// Round 8
// 116.006 us; speedup vs baseline: 1.1802x; 1.0273x over previous
//
#include <hip/hip_runtime.h>
#include <hip/hip_fp16.h>

// Problem constants
#define Wd    96
#define Hd    96
#define HW    9216           // 96*96
#define Bn    4
#define Cn    64             // channels per section
#define C3    192            // 3*Cn
#define On    64             // out channels
#define NPIX  (Bn*HW)        // 36864
#define NFEAT (Bn*Cn*HW)     // 2359296 elements per output tensor
#define NWTB  (9*6*4*512)    // 110592 f16 frag-linear deform weights
#define NWTB2 (18*2*64*8)    // 18432 f16 frag-linear offset weights
#define NRB3  (Bn*(HW/32))   // 1152 repack blocks (32-px strips)

// Halo geometry: 16x2 px tile -> rows yb-2..yb+3, cols xb-3..xb+17
#define HR2   6
#define HC    21
#define HPITCH 400           // bytes per staged pixel (384 + 16 pad)
#define NPR2  (HR2*HC)       // 126 staged pixel rows
#define SELEM (NPR2*24)      // 3024 f4v staging elements
#define HALO_B (NPR2*HPITCH) // 50400
#define NFBLK 1152           // fused blocks (6 x 48 x 4)

typedef __attribute__((ext_vector_type(8))) short s8v;       // 8 f16 (raw bits)
typedef __attribute__((ext_vector_type(8))) _Float16 h8v;    // 8 f16 (MFMA operand)
typedef __attribute__((ext_vector_type(4))) unsigned int u4v;
typedef __attribute__((ext_vector_type(4))) float f4v;       // MFMA accum / float4

__device__ __forceinline__ unsigned packh(float lo, float hi) {
    __half2 h = __floats2half2_rn(lo, hi);
    return __builtin_bit_cast(unsigned, h);
}

// ===========================================================================
// repack_wts: blocks [0, NRB3): NCHW -> f16 NHWC packed + fused diff.
// blocks [NRB3, ...): weight repacks. Final packed stores vectorized
// (3 dwordx4 per thread instead of 12 scattered dwords).
// ===========================================================================
__global__ __launch_bounds__(256) void repack_wts_kernel(
        const float* __restrict__ ref,
        const float* __restrict__ dist,
        unsigned int* __restrict__ packed,    // [NPIX][96] f16-pairs
        float* __restrict__ out_diff,
        const float* __restrict__ dw,
        const float* __restrict__ ow,
        __half* __restrict__ wtb,
        __half* __restrict__ wtb2) {
    __shared__ unsigned lds[96][33];          // 12672 B, odd stride

    int tid = threadIdx.x;

    if (blockIdx.x >= NRB3) {
        int e = (int)(blockIdx.x - NRB3) * 256 + tid;
        if (e < NWTB) {
            int j = e & 7;
            int L = (e >> 3) & 63;
            int mt = (e >> 9) & 3;
            int rest = e >> 11;
            int kc = rest % 6;
            int tap = rest / 6;
            int o = mt * 16 + (L & 15);
            int c = kc * 32 + (L >> 4) * 8 + j;
            wtb[e] = __float2half(dw[((size_t)o * C3 + c) * 9 + tap]);
        } else if (e < NWTB + NWTB2) {
            int e2 = e - NWTB;
            int j = e2 & 7;
            int L = (e2 >> 3) & 63;
            int mt = (e2 >> 9) & 1;
            int kc2 = e2 >> 10;           // 0..17 = t*2+kc
            int v = mt * 16 + (L & 15);
            int k = kc2 * 32 + ((L >> 4) & 3) * 8 + j;
            int c = k & 63;
            int tap = k >> 6;
            float val = (v < 18) ? ow[((size_t)v * Cn + c) * 9 + tap] : 0.f;
            wtb2[e2] = __float2half(val);
        }
        return;
    }

    // ---- repack part: 32-px strip ----
    int blk = blockIdx.x;
    int b = blk / (HW / 32);
    int pb = (blk - b * (HW / 32)) * 32;
    int pxg = tid & 7;                        // 8 px-quads of 4
    int chp = tid >> 3;                       // channel pair 0..31

    size_t base0 = ((size_t)(b * Cn + 2 * chp)) * HW + pb + pxg * 4;
    size_t base1 = base0 + HW;

    f4v r0 = *(const f4v*)(ref + base0);
    f4v r1 = *(const f4v*)(ref + base1);
    f4v d0 = *(const f4v*)(dist + base0);
    f4v d1 = *(const f4v*)(dist + base1);

    f4v q0 = (r0 - d0) * (r0 - d0);
    f4v q1 = (r1 - d1) * (r1 - d1);
    *(f4v*)(out_diff + base0) = q0;
    *(f4v*)(out_diff + base1) = q1;

#pragma unroll
    for (int j = 0; j < 4; ++j) {
        int p = pxg * 4 + j;
        lds[chp][p]      = packh(r0[j], r1[j]);
        lds[32 + chp][p] = packh(d0[j], d1[j]);
        lds[64 + chp][p] = packh(q0[j], q1[j]);
    }
    __syncthreads();

    // vectorized transpose-out: thread owns (px, 12-ch-pair slab)
    {
        int p = tid >> 3;                     // 0..31
        int part = tid & 7;                   // 0..7
        unsigned* pko = packed + ((size_t)(b * HW + pb) + p) * 96 + part * 12;
#pragma unroll
        for (int q = 0; q < 3; ++q) {
            u4v w;
#pragma unroll
            for (int j = 0; j < 4; ++j)
                w[j] = lds[part * 12 + q * 4 + j][p];
            *(u4v*)(pko + q * 4) = w;
        }
    }
}

// ===========================================================================
// fused_mfma: 16x2 px tile, 384 thr = 2 row-groups x 3-way split-K (Phase B).
// Phase A (offset conv) now computed by ONE wave per row-group (all 9 taps,
// 36 MFMA) -> no redA buffer, one fewer barrier. LDS 52.7 KB -> 3 blocks/CU
// = 4.5 waves/SIMD (was 2 blocks / 3 waves). Phase-B reduction aliases halo.
// ===========================================================================
struct Ctx {
    int o00, o01, o10, o11;      // global byte offsets (fallback path)
    int l00, l01, l10, l11;      // LDS byte offsets (fast path)
    float W00, W01, W10, W11;
    int inh;                     // all 4 corners inside staged halo
};

__device__ __forceinline__ Ctx mkctx(int t, int y, int x, int xb, int yb,
                                     float2 o2) {
    Ctx c;
    float py = (float)(y - 1 + t / 3) + o2.x;
    float pxs = (float)(x - 1 + t % 3) + o2.y;
    float fy = floorf(py), fx = floorf(pxs);
    int y0 = (int)fy, x0 = (int)fx;
    int y1 = y0 + 1, x1 = x0 + 1;
    float ay = py - fy, ax = pxs - fx;
    bool vy0 = (unsigned)y0 < (unsigned)Hd;
    bool vy1 = (unsigned)y1 < (unsigned)Hd;
    bool vx0 = (unsigned)x0 < (unsigned)Wd;
    bool vx1 = (unsigned)x1 < (unsigned)Wd;
    c.W00 = (vy0 && vx0) ? (1.f - ay) * (1.f - ax) : 0.f;
    c.W01 = (vy0 && vx1) ? (1.f - ay) * ax : 0.f;
    c.W10 = (vy1 && vx0) ? ay * (1.f - ax) : 0.f;
    c.W11 = (vy1 && vx1) ? ay * ax : 0.f;
    int y0c = min(max(y0, 0), Hd - 1), y1c = min(max(y1, 0), Hd - 1);
    int x0c = min(max(x0, 0), Wd - 1), x1c = min(max(x1, 0), Wd - 1);
    c.o00 = (y0c * Wd + x0c) * (C3 * 2);
    c.o01 = (y0c * Wd + x1c) * (C3 * 2);
    c.o10 = (y1c * Wd + x0c) * (C3 * 2);
    c.o11 = (y1c * Wd + x1c) * (C3 * 2);
    int iy0 = y0c - yb + 2, iy1 = y1c - yb + 2;      // halo row 0 = yb-2
    int ix0 = x0c - xb + 3, ix1 = x1c - xb + 3;
    c.inh = ((unsigned)iy0 < (unsigned)HR2) & ((unsigned)iy1 < (unsigned)HR2) &
            ((unsigned)ix0 < (unsigned)HC) & ((unsigned)ix1 < (unsigned)HC);
    c.l00 = (iy0 * HC + ix0) * HPITCH;
    c.l01 = (iy0 * HC + ix1) * HPITCH;
    c.l10 = (iy1 * HC + ix0) * HPITCH;
    c.l11 = (iy1 * HC + ix1) * HPITCH;
    return c;
}

__device__ __forceinline__ __half2 uh2(unsigned u) {
    return __builtin_bit_cast(__half2, u);
}

// Bilinear blend on packed f16 pairs + 4 MFMAs, for one (tap, kc-triple).
__device__ __forceinline__ void bilin_mfma(const s8v* rw, const Ctx& cc,
        const s8v* __restrict__ Ap, int t, int kb, int L, f4v* acc) {
    __half2 w00 = __float2half2_rn(cc.W00);
    __half2 w01 = __float2half2_rn(cc.W01);
    __half2 w10 = __float2half2_rn(cc.W10);
    __half2 w11 = __float2half2_rn(cc.W11);
#pragma unroll
    for (int i = 0; i < 3; ++i) {
        int kc = kb + i;
        u4v u00 = __builtin_bit_cast(u4v, rw[0 * 3 + i]);
        u4v u01 = __builtin_bit_cast(u4v, rw[1 * 3 + i]);
        u4v u10 = __builtin_bit_cast(u4v, rw[2 * 3 + i]);
        u4v u11 = __builtin_bit_cast(u4v, rw[3 * 3 + i]);
        u4v bu;
#pragma unroll
        for (int p = 0; p < 4; ++p) {
            __half2 v = __hmul2(uh2(u00[p]), w00);
            v = __hfma2(uh2(u01[p]), w01, v);
            v = __hfma2(uh2(u10[p]), w10, v);
            v = __hfma2(uh2(u11[p]), w11, v);
            bu[p] = __builtin_bit_cast(unsigned, v);
        }
        h8v bfrag = __builtin_bit_cast(h8v, bu);
#pragma unroll
        for (int mt = 0; mt < 4; ++mt) {
            h8v a = __builtin_bit_cast(h8v, Ap[((t * 6 + kc) * 4 + mt) * 64 + L]);
            acc[mt] = __builtin_amdgcn_mfma_f32_16x16x32_f16(a, bfrag, acc[mt], 0, 0, 0);
        }
    }
}

__global__ __launch_bounds__(384, 4) void fused_mfma(
        const __half* __restrict__ packed,
        const __half* __restrict__ wtb2,
        const float* __restrict__ ob,
        const __half* __restrict__ wtb,
        const float* __restrict__ db,
        float* __restrict__ out) {
    __shared__ __align__(16) char smem[HALO_B + 2 * 16 * 18 * 4];   // 52704 B
    f4v* halo = (f4v*)smem;                               // 50400 B
    float (*off_l)[18] = (float(*)[18])(smem + HALO_B);   // [32][18], 2304 B
    float* redB = (float*)smem;                           // aliases halo

    int tid = threadIdx.x;
    int L = tid & 63;
    int wv = tid >> 6;                        // 0..5
    int g  = wv / 3;                          // row group 0..1
    int kv = wv - g * 3;                      // split-K 0..2 (Phase B)
    int px = L & 15;
    int lg = L >> 4;
    int blk = blockIdx.x;
    int region = (blk & 7) * 144 + (blk >> 3);        // 1152 blocks, XCD swizzle
    int b = region / 288;
    int rt = region - b * 288;
    int yt = rt / 6;
    int xt = rt - yt * 6;
    int yb = yt * 2, xb = xt * 16;            // tile: rows yb..yb+1, cols xb..+15
    int y = yb + g, x = xb + px;
    int pb = y * Wd + xb;                     // this group's output row base
    int tbase = kv * 3;

    const char* pkb = (const char*)packed + (size_t)b * HW * (C3 * 2);
    const char* hb = (const char*)halo;

    // ---------------- stage halo: 3024 f4v, fully unrolled batch -----------
    {
        f4v stg[8];
        int slot[8];
#pragma unroll
        for (int k = 0; k < 8; ++k) {
            int i = tid + k * 384;
            bool act = (k < 7) ? true : (tid < SELEM - 7 * 384);
            int pr = i / 24, ck = i - pr * 24;
            int iy = pr / HC, ix = pr - iy * HC;
            int gy = min(max(yb - 2 + iy, 0), Hd - 1);
            int gx = min(max(xb - 3 + ix, 0), Wd - 1);
            slot[k] = act ? (pr * (HPITCH / 16) + ck) : -1;
            if (act)
                stg[k] = *(const f4v*)(pkb + ((size_t)(gy * Wd + gx)) * (C3 * 2) + ck * 16);
        }
#pragma unroll
        for (int k = 0; k < 8; ++k)
            if (slot[k] >= 0) halo[slot[k]] = stg[k];
    }
    __syncthreads();

    // ------- Phase A: offset conv — ONE wave per row-group, all 9 taps -----
    if (kv == 0) {
        const s8v* Ap = (const s8v*)wtb2;
        f4v acc0 = {0.f, 0.f, 0.f, 0.f};
        f4v acc1 = {0.f, 0.f, 0.f, 0.f};
#pragma unroll
        for (int t = 0; t < 9; ++t) {
            int ty = t / 3, tx = t - ty * 3;
            int yy = y - 1 + ty, xx = x - 1 + tx;
            bool val = (unsigned)yy < (unsigned)Hd && (unsigned)xx < (unsigned)Wd;
            short m = val ? (short)-1 : (short)0;
            int lofs = ((g + 1 + ty) * HC + (px + 2 + tx)) * HPITCH + lg * 16;
#pragma unroll
            for (int kc = 0; kc < 2; ++kc) {
                s8v braw = *(const s8v*)(hb + lofs + kc * 64) & m;
                h8v bfrag = __builtin_bit_cast(h8v, braw);
                h8v a0 = __builtin_bit_cast(h8v, Ap[((t * 2 + kc) * 2 + 0) * 64 + L]);
                h8v a1 = __builtin_bit_cast(h8v, Ap[((t * 2 + kc) * 2 + 1) * 64 + L]);
                acc0 = __builtin_amdgcn_mfma_f32_16x16x32_f16(a0, bfrag, acc0, 0, 0, 0);
                acc1 = __builtin_amdgcn_mfma_f32_16x16x32_f16(a1, bfrag, acc1, 0, 0, 0);
            }
        }
#pragma unroll
        for (int r = 0; r < 4; ++r) {
            int v = lg * 4 + r;
            off_l[g * 16 + px][v] = acc0[r] + ob[v];
        }
        if (lg == 0) {
#pragma unroll
            for (int r = 0; r < 2; ++r)
                off_l[g * 16 + px][16 + r] = acc1[r] + ob[16 + r];
        }
    }
    __syncthreads();

    // ---------------- Phase B: deform conv ----------------
    const s8v* Ap = (const s8v*)wtb;

    Ctx ctx[3];
    int ok = 1;
#pragma unroll
    for (int tt = 0; tt < 3; ++tt) {
        int t = tbase + tt;
        float2 o2 = {off_l[g * 16 + px][2 * t], off_l[g * 16 + px][2 * t + 1]};
        ctx[tt] = mkctx(t, y, x, xb, yb, o2);
        ok &= ctx[tt].inh;
    }

    f4v acc[4];
    acc[0] = acc[1] = acc[2] = acc[3] = (f4v){0.f, 0.f, 0.f, 0.f};

    if (__all(ok)) {
        // fast path: bilinear gathers from LDS halo
#pragma unroll
        for (int h = 0; h < 6; ++h) {             // 3 taps x 2 halves
            int tt = h >> 1;
            int t = tbase + tt;
            int kb = (h & 1) * 3;
            const Ctx cc = ctx[tt];
            s8v rw[12];
#pragma unroll
            for (int i = 0; i < 3; ++i) {
                int co = ((kb + i) * 4 + lg) * 16;
                rw[0 * 3 + i] = *(const s8v*)(hb + cc.l00 + co);
                rw[1 * 3 + i] = *(const s8v*)(hb + cc.l01 + co);
                rw[2 * 3 + i] = *(const s8v*)(hb + cc.l10 + co);
                rw[3 * 3 + i] = *(const s8v*)(hb + cc.l11 + co);
            }
            bilin_mfma(rw, cc, Ap, t, kb, L, acc);
        }
    } else {
        // fallback: global gathers (rare; arbitrary offsets stay correct)
#pragma unroll
        for (int h = 0; h < 6; ++h) {
            int tt = h >> 1;
            int t = tbase + tt;
            int kb = (h & 1) * 3;
            const Ctx cc = ctx[tt];
            s8v rw[12];
#pragma unroll
            for (int i = 0; i < 3; ++i) {
                int co = ((kb + i) * 4 + lg) * 16;
                rw[0 * 3 + i] = *(const s8v*)(pkb + cc.o00 + co);
                rw[1 * 3 + i] = *(const s8v*)(pkb + cc.o01 + co);
                rw[2 * 3 + i] = *(const s8v*)(pkb + cc.o10 + co);
                rw[3 * 3 + i] = *(const s8v*)(pkb + cc.o11 + co);
            }
            bilin_mfma(rw, cc, Ap, t, kb, L, acc);
        }
    }

    // -------- reduction: redB aliases halo (all halo reads done) -----------
    __syncthreads();
    if (kv != 0) {
        float* r = redB + ((g * 2 + kv - 1) * 64 + L) * 17;
#pragma unroll
        for (int mt = 0; mt < 4; ++mt)
#pragma unroll
            for (int q = 0; q < 4; ++q)
                r[mt * 4 + q] = acc[mt][q];
    }
    __syncthreads();
    if (kv == 0) {
        const float* r0 = redB + ((g * 2 + 0) * 64 + L) * 17;
        const float* r1 = redB + ((g * 2 + 1) * 64 + L) * 17;
#pragma unroll
        for (int mt = 0; mt < 4; ++mt) {
#pragma unroll
            for (int q = 0; q < 4; ++q) {
                int o = mt * 16 + lg * 4 + q;
                float v = acc[mt][q] + r0[mt * 4 + q] + r1[mt * 4 + q] + db[o];
                out[((size_t)(b * On + o)) * HW + pb + px] = fmaxf(v, 0.f);
            }
        }
    }
}

// ---------------------------------------------------------------------------
extern "C" void kernel_launch(void* const* d_in, const int* in_sizes, int n_in,
                              void* d_out, int out_size, void* d_ws, size_t ws_size,
                              hipStream_t stream) {
    const float* ref  = (const float*)d_in[0];
    const float* dist = (const float*)d_in[1];
    const float* ow   = (const float*)d_in[2];
    const float* ob   = (const float*)d_in[3];
    const float* dw   = (const float*)d_in[4];
    const float* db   = (const float*)d_in[5];

    float* out = (float*)d_out;               // [feat | diff], each NFEAT f32

    // ws: wtb f16 | wtb2 f16 | packed f16 [NPIX][192]
    __half* ws_wtb  = (__half*)d_ws;
    __half* ws_wtb2 = ws_wtb + NWTB;
    __half* ws_pk   = ws_wtb2 + NWTB2;

    int wts_blocks = (NWTB + NWTB2 + 255) / 256;      // 504
    repack_wts_kernel<<<NRB3 + wts_blocks, 256, 0, stream>>>(
        ref, dist, (unsigned int*)ws_pk, out + NFEAT, dw, ow, ws_wtb, ws_wtb2);
    fused_mfma<<<NFBLK, 384, 0, stream>>>(
        ws_pk, ws_wtb2, ob, ws_wtb, db, out);
}